// Round 9
// baseline (5442.170 us; speedup 1.0000x reference)
//
#include <hip/hip_runtime.h>

#define BATCH 64
#define LEN   2048
#define NIN   128
#define NH    256

typedef float f32x4 __attribute__((ext_vector_type(4)));

// ---------------------------------------------------------------------------
// FROZEN ARITHMETIC (R7: absmax == 0.0). Do not touch:
//  - dots: single-accumulator, k-ascending fmaf chains from 0
//  - pre = (xw + acc) + bias, left-assoc, no contraction
//  - tanh = EmitFastTanh(with_fma=true): clamp ±7.99881172180175781,
//    fmaf Horner, IEEE f32 divide, |x|<0.0004 passthrough
// ---------------------------------------------------------------------------
__device__ __forceinline__ float tanh_xla_fma_f32(float x) {
  const float kClamp = 7.99881172180175781f;
  float xc = fmaxf(x, -kClamp);
  xc = fminf(xc, kClamp);
  float x2 = xc * xc;
  float num = fmaf(x2, -2.76076847742355e-16f, 2.00018790482477e-13f);
  num = fmaf(x2, num, -8.60467152213735e-11f);
  num = fmaf(x2, num, 5.12229709037114e-08f);
  num = fmaf(x2, num, 1.48572235717979e-05f);
  num = fmaf(x2, num, 6.37261928875436e-04f);
  num = fmaf(x2, num, 4.89352455891786e-03f);
  num = xc * num;
  float den = fmaf(x2, 1.19825839466702e-06f, 1.18534705686654e-04f);
  den = fmaf(x2, den, 2.26843463243900e-03f);
  den = fmaf(x2, den, 4.89352518554385e-03f);
  float r = num / den;
  return (fabsf(x) < 0.0004f) ? x : r;
}

#define REP32(M) M(0) M(1) M(2) M(3) M(4) M(5) M(6) M(7) \
  M(8) M(9) M(10) M(11) M(12) M(13) M(14) M(15) \
  M(16) M(17) M(18) M(19) M(20) M(21) M(22) M(23) \
  M(24) M(25) M(26) M(27) M(28) M(29) M(30) M(31)
#define REP64(M) REP32(M) M(32) M(33) M(34) M(35) M(36) M(37) M(38) M(39) \
  M(40) M(41) M(42) M(43) M(44) M(45) M(46) M(47) \
  M(48) M(49) M(50) M(51) M(52) M(53) M(54) M(55) \
  M(56) M(57) M(58) M(59) M(60) M(61) M(62) M(63)

// Pin a loaded value into VGPRs: an asm-redefined value cannot be
// rematerialized (the RA would otherwise re-issue the invariant
// global_load inside the loop instead of keeping it live — R7/R8's
// VGPR_Count=140 / 200-cyc-per-float4 reload stall).
#define PIN(v) asm("" : "+v"(v));

// ---------------------------------------------------------------------------
// Kernel A: xw[l][b][h] = sum_i x[b][l][i] * Wx[h][i]
// 32 pinned f32x4 weights in VGPRs; x-row loads are block-uniform;
// strict i-ascending fmaf chain (frozen).
// ---------------------------------------------------------------------------
constexpr int LC = 128;   // l-positions per block

__global__ __launch_bounds__(256, 2)
void xw_kernel(const float* __restrict__ x, const float* __restrict__ Wx,
               float* __restrict__ out) {
  const int j  = threadIdx.x;
  const int b  = blockIdx.x & (BATCH - 1);
  const int lt = blockIdx.x >> 6;

  const f32x4* wrow = (const f32x4*)&Wx[(size_t)j * NIN];
#define XWDECL(n) f32x4 xw##n = wrow[n]; PIN(xw##n)
  REP32(XWDECL)
#undef XWDECL

  const float* xr = x + ((size_t)b * LEN + (size_t)lt * LC) * NIN;
  float* op = out + ((size_t)lt * LC * BATCH + b) * NH + j;

  for (int ll = 0; ll < LC; ++ll) {
    const float* xrow = xr + (size_t)ll * NIN;   // block-uniform address
    float acc = 0.0f;
#define XWSTEP(n) { \
      acc = fmaf(xrow[4*(n)    ], xw##n.x, acc); \
      acc = fmaf(xrow[4*(n) + 1], xw##n.y, acc); \
      acc = fmaf(xrow[4*(n) + 2], xw##n.z, acc); \
      acc = fmaf(xrow[4*(n) + 3], xw##n.w, acc); }
    REP32(XWSTEP)
#undef XWSTEP
    op[(size_t)ll * BATCH * NH] = acc;
  }
}

// ---------------------------------------------------------------------------
// Kernel B: recurrence. One batch/block, 256 threads (4 waves, 1 wave/SIMD;
// launch_bounds(256,1) -> 512-VGPR budget). W_h row j = 64 PINNED f32x4 in
// VGPRs (~300 VGPRs, no remat, no spill). Hidden state double-buffered in
// LDS; h reads are same-address broadcasts (conflict-free). Custom barrier:
// lgkmcnt(0)-only wait + raw s_barrier (global store stays in flight).
// ---------------------------------------------------------------------------
__global__ __launch_bounds__(256, 1)
void rnn_kernel(const float* __restrict__ Wh, const float* __restrict__ bh,
                const float* __restrict__ h0, float* __restrict__ io) {
  const int b = blockIdx.x;
  const int j = threadIdx.x;

  __shared__ __align__(16) float hbuf[2][NH];

  const f32x4* wrow = (const f32x4*)&Wh[(size_t)j * NH];
#define WDECL(n) f32x4 wv##n = wrow[n]; PIN(wv##n)
  REP64(WDECL)
#undef WDECL

  const float bias = bh[j];
  hbuf[0][j] = h0[b * NH + j];
  __syncthreads();

  float* p = io + (size_t)b * NH + j;
  const size_t stride = (size_t)BATCH * NH;

  float xw = p[0];
  int cur = 0;

  for (int l = 0; l < LEN; ++l) {
    const int ln = (l + 1 < LEN) ? (l + 1) : l;
    const float xw_next = p[(size_t)ln * stride];   // prefetch next xw

    const f32x4* hb = (const f32x4*)&hbuf[cur][0];
    float acc = 0.0f;
#define WSTEP(n) { f32x4 h4 = hb[n]; \
      acc = fmaf(h4.x, wv##n.x, acc); \
      acc = fmaf(h4.y, wv##n.y, acc); \
      acc = fmaf(h4.z, wv##n.z, acc); \
      acc = fmaf(h4.w, wv##n.w, acc); }
    REP64(WSTEP)
#undef WSTEP

    float pre;
    {
#pragma clang fp contract(off)
      pre = (xw + acc) + bias;                  // ((xw + hW) + b) order
    }
    const float hn = tanh_xla_fma_f32(pre);

    p[(size_t)l * stride] = hn;                 // fire-and-forget store
    hbuf[cur ^ 1][j] = hn;                      // publish state

    // lgkmcnt-only barrier: LDS write visible, global store in flight.
    asm volatile("s_waitcnt lgkmcnt(0)" ::: "memory");
    __builtin_amdgcn_s_barrier();
    asm volatile("" ::: "memory");

    cur ^= 1;
    xw = xw_next;
  }
}

extern "C" void kernel_launch(void* const* d_in, const int* in_sizes, int n_in,
                              void* d_out, int out_size, void* d_ws, size_t ws_size,
                              hipStream_t stream) {
  // Resolve inputs BY SIZE (all element counts distinct).
  const float* x  = (const float*)d_in[0];  // 16777216
  const float* h0 = (const float*)d_in[1];  // 16384
  const float* Wx = (const float*)d_in[2];  // 32768
  const float* Wh = (const float*)d_in[3];  // 65536
  const float* bh = (const float*)d_in[4];  // 256
  for (int i = 0; i < n_in; ++i) {
    switch (in_sizes[i]) {
      case 16777216: x  = (const float*)d_in[i]; break;
      case 16384:    h0 = (const float*)d_in[i]; break;
      case 32768:    Wx = (const float*)d_in[i]; break;
      case 65536:    Wh = (const float*)d_in[i]; break;
      case 256:      bh = (const float*)d_in[i]; break;
      default: break;
    }
  }
  float* out = (float*)d_out;               // [2048, 64, 256] f32

  xw_kernel<<<dim3((LEN / LC) * BATCH), dim3(256), 0, stream>>>(x, Wx, out);
  rnn_kernel<<<dim3(BATCH), dim3(256), 0, stream>>>(Wh, bh, h0, out);
}

// Round 10
// 3676.027 us; speedup vs baseline: 1.4804x; 1.4804x over previous
//
#include <hip/hip_runtime.h>

#define BATCH 64
#define LEN   2048
#define NIN   128
#define NH    256

typedef float f32x4 __attribute__((ext_vector_type(4)));

// ---------------------------------------------------------------------------
// FROZEN ARITHMETIC (R7: absmax == 0.0). Do not touch:
//  - dots: single-accumulator, k-ascending fmaf chains from 0
//  - pre = (xw + acc) + bias, left-assoc, no contraction
//  - tanh = EmitFastTanh(with_fma=true): clamp ±7.99881172180175781,
//    fmaf Horner, IEEE f32 divide, |x|<0.0004 passthrough
// ---------------------------------------------------------------------------
__device__ __forceinline__ float tanh_xla_fma_f32(float x) {
  const float kClamp = 7.99881172180175781f;
  float xc = fmaxf(x, -kClamp);
  xc = fminf(xc, kClamp);
  float x2 = xc * xc;
  float num = fmaf(x2, -2.76076847742355e-16f, 2.00018790482477e-13f);
  num = fmaf(x2, num, -8.60467152213735e-11f);
  num = fmaf(x2, num, 5.12229709037114e-08f);
  num = fmaf(x2, num, 1.48572235717979e-05f);
  num = fmaf(x2, num, 6.37261928875436e-04f);
  num = fmaf(x2, num, 4.89352455891786e-03f);
  num = xc * num;
  float den = fmaf(x2, 1.19825839466702e-06f, 1.18534705686654e-04f);
  den = fmaf(x2, den, 2.26843463243900e-03f);
  den = fmaf(x2, den, 4.89352518554385e-03f);
  float r = num / den;
  return (fabsf(x) < 0.0004f) ? x : r;
}

// gfx950 register model: 256 ARCH VGPRs max per wave (v0-v255); AGPRs are a
// second 256-reg file (unified 512 budget). 64 resident float4 weights
// (256 regs) + working set CANNOT fit in arch VGPRs (R8/R9: RA spilled,
// VGPR_Count pinned at ~140). Fix: hold most weights in AGPRs.
//   - prologue: v_accvgpr_write_b32 (asm, non-volatile: schedules freely)
//   - loop:     v_accvgpr_read_b32 (asm VOLATILE: LICM must not hoist the
//               loop-invariant copies back into VGPR live ranges)
// Issue math: 256 fma*2cyc + 224 reads*2cyc = 960 cyc <= 1024-cyc chain
// latency shadow -> reads are free at 1 wave/SIMD.

#define PINV(v) asm("" : "+v"(v));

#define REPA56(M) M(0) M(1) M(2) M(3) M(4) M(5) M(6) M(7) \
  M(8) M(9) M(10) M(11) M(12) M(13) M(14) M(15) \
  M(16) M(17) M(18) M(19) M(20) M(21) M(22) M(23) \
  M(24) M(25) M(26) M(27) M(28) M(29) M(30) M(31) \
  M(32) M(33) M(34) M(35) M(36) M(37) M(38) M(39) \
  M(40) M(41) M(42) M(43) M(44) M(45) M(46) M(47) \
  M(48) M(49) M(50) M(51) M(52) M(53) M(54) M(55)
#define REPV8(M) M(56) M(57) M(58) M(59) M(60) M(61) M(62) M(63)

#define REPA28(M) M(0) M(1) M(2) M(3) M(4) M(5) M(6) M(7) \
  M(8) M(9) M(10) M(11) M(12) M(13) M(14) M(15) \
  M(16) M(17) M(18) M(19) M(20) M(21) M(22) M(23) \
  M(24) M(25) M(26) M(27)
#define REPV4(M) M(28) M(29) M(30) M(31)

#define AG_DECL(n) float ag##n##x, ag##n##y, ag##n##z, ag##n##w;
#define AG_LOAD(n) { f32x4 v = wrow[n]; \
  asm("v_accvgpr_write_b32 %0, %1" : "=a"(ag##n##x) : "v"(v.x)); \
  asm("v_accvgpr_write_b32 %0, %1" : "=a"(ag##n##y) : "v"(v.y)); \
  asm("v_accvgpr_write_b32 %0, %1" : "=a"(ag##n##z) : "v"(v.z)); \
  asm("v_accvgpr_write_b32 %0, %1" : "=a"(ag##n##w) : "v"(v.w)); }
// Frozen chain order: k ascending within and across quads.
#define AG_STEP(n, src) { f32x4 h4 = (src); float t; \
  asm volatile("v_accvgpr_read_b32 %0, %1" : "=v"(t) : "a"(ag##n##x)); \
  acc = fmaf(h4.x, t, acc); \
  asm volatile("v_accvgpr_read_b32 %0, %1" : "=v"(t) : "a"(ag##n##y)); \
  acc = fmaf(h4.y, t, acc); \
  asm volatile("v_accvgpr_read_b32 %0, %1" : "=v"(t) : "a"(ag##n##z)); \
  acc = fmaf(h4.z, t, acc); \
  asm volatile("v_accvgpr_read_b32 %0, %1" : "=v"(t) : "a"(ag##n##w)); \
  acc = fmaf(h4.w, t, acc); }
#define VV_DECL(n) f32x4 wv##n;
#define VV_LOAD(n) wv##n = wrow[n]; PINV(wv##n)
#define VV_STEP(n, src) { f32x4 h4 = (src); \
  acc = fmaf(h4.x, wv##n.x, acc); \
  acc = fmaf(h4.y, wv##n.y, acc); \
  acc = fmaf(h4.z, wv##n.z, acc); \
  acc = fmaf(h4.w, wv##n.w, acc); }

// ---------------------------------------------------------------------------
// Kernel A: xw[l][b][h] = sum_i x[b][l][i] * Wx[h][i]
// 28 AGPR quads + 4 pinned VGPR quads per thread. x-row loads are
// block-uniform (scalarizable to SMEM). Strict i-ascending fmaf chain.
// ---------------------------------------------------------------------------
constexpr int LC = 128;   // l-positions per block

__global__ __launch_bounds__(256, 2)
void xw_kernel(const float* __restrict__ x, const float* __restrict__ Wx,
               float* __restrict__ out) {
  const int j  = threadIdx.x;
  const int b  = blockIdx.x & (BATCH - 1);
  const int lt = blockIdx.x >> 6;

  const f32x4* wrow = (const f32x4*)&Wx[(size_t)j * NIN];
  REPA28(AG_DECL)
  REPV4(VV_DECL)
  REPA28(AG_LOAD)
  REPV4(VV_LOAD)

  const float* xr = x + ((size_t)b * LEN + (size_t)lt * LC) * NIN;
  const f32x4* xr4 = (const f32x4*)xr;
  float* op = out + ((size_t)lt * LC * BATCH + b) * NH + j;

  for (int ll = 0; ll < LC; ++ll) {
    const f32x4* xrow = xr4 + (size_t)ll * (NIN / 4);  // block-uniform
    float acc = 0.0f;
#define XSTEP_A(n) AG_STEP(n, xrow[n])
#define XSTEP_V(n) VV_STEP(n, xrow[n])
    REPA28(XSTEP_A)
    REPV4(XSTEP_V)
#undef XSTEP_A
#undef XSTEP_V
    op[(size_t)ll * BATCH * NH] = acc;
  }
}

// ---------------------------------------------------------------------------
// Kernel B: recurrence. One batch/block, 256 threads (4 waves, 1 wave/SIMD;
// launch_bounds(256,1)). W_h row j: 56 AGPR quads (224) + 8 pinned VGPR
// quads (32) -> VGPR ~70 + AGPR 224 = ~294 of 512 unified, both files under
// their 256 caps. Hidden state double-buffered in LDS (broadcast reads,
// conflict-free). lgkmcnt-only barrier (global store stays in flight).
// ---------------------------------------------------------------------------
__global__ __launch_bounds__(256, 1)
void rnn_kernel(const float* __restrict__ Wh, const float* __restrict__ bh,
                const float* __restrict__ h0, float* __restrict__ io) {
  const int b = blockIdx.x;
  const int j = threadIdx.x;

  __shared__ __align__(16) float hbuf[2][NH];

  const f32x4* wrow = (const f32x4*)&Wh[(size_t)j * NH];
  REPA56(AG_DECL)
  REPV8(VV_DECL)
  REPA56(AG_LOAD)
  REPV8(VV_LOAD)

  const float bias = bh[j];
  hbuf[0][j] = h0[b * NH + j];
  __syncthreads();

  float* p = io + (size_t)b * NH + j;
  const size_t stride = (size_t)BATCH * NH;

  float xw = p[0];
  int cur = 0;

  for (int l = 0; l < LEN; ++l) {
    const int ln = (l + 1 < LEN) ? (l + 1) : l;
    const float xw_next = p[(size_t)ln * stride];   // prefetch next xw

    const f32x4* hb = (const f32x4*)&hbuf[cur][0];
    float acc = 0.0f;
#define HSTEP_A(n) AG_STEP(n, hb[n])
#define HSTEP_V(n) VV_STEP(n, hb[n])
    REPA56(HSTEP_A)
    REPV8(HSTEP_V)
#undef HSTEP_A
#undef HSTEP_V

    float pre;
    {
#pragma clang fp contract(off)
      pre = (xw + acc) + bias;                  // ((xw + hW) + b) order
    }
    const float hn = tanh_xla_fma_f32(pre);

    p[(size_t)l * stride] = hn;                 // fire-and-forget store
    hbuf[cur ^ 1][j] = hn;                      // publish state

    // lgkmcnt-only barrier: LDS visible, global store left in flight.
    asm volatile("s_waitcnt lgkmcnt(0)" ::: "memory");
    __builtin_amdgcn_s_barrier();
    asm volatile("" ::: "memory");

    cur ^= 1;
    xw = xw_next;
  }
}

extern "C" void kernel_launch(void* const* d_in, const int* in_sizes, int n_in,
                              void* d_out, int out_size, void* d_ws, size_t ws_size,
                              hipStream_t stream) {
  // Resolve inputs BY SIZE (all element counts distinct).
  const float* x  = (const float*)d_in[0];  // 16777216
  const float* h0 = (const float*)d_in[1];  // 16384
  const float* Wx = (const float*)d_in[2];  // 32768
  const float* Wh = (const float*)d_in[3];  // 65536
  const float* bh = (const float*)d_in[4];  // 256
  for (int i = 0; i < n_in; ++i) {
    switch (in_sizes[i]) {
      case 16777216: x  = (const float*)d_in[i]; break;
      case 16384:    h0 = (const float*)d_in[i]; break;
      case 32768:    Wx = (const float*)d_in[i]; break;
      case 65536:    Wh = (const float*)d_in[i]; break;
      case 256:      bh = (const float*)d_in[i]; break;
      default: break;
    }
  }
  float* out = (float*)d_out;               // [2048, 64, 256] f32

  xw_kernel<<<dim3((LEN / LC) * BATCH), dim3(256), 0, stream>>>(x, Wx, out);
  rnn_kernel<<<dim3(BATCH), dim3(256), 0, stream>>>(Wh, bh, h0, out);
}

// Round 11
// 3642.738 us; speedup vs baseline: 1.4940x; 1.0091x over previous
//
#include <hip/hip_runtime.h>

#define BATCH 64
#define LEN   2048
#define NIN   128
#define NH    256

typedef float f32x4 __attribute__((ext_vector_type(4)));

// ---------------------------------------------------------------------------
// FROZEN ARITHMETIC (R7: absmax == 0.0). Do not touch:
//  - dots: single-accumulator, k-ascending fmaf chains from 0
//  - pre = (xw + acc) + bias, left-assoc, no contraction
//  - tanh = EmitFastTanh(with_fma=true): clamp ±7.99881172180175781,
//    fmaf Horner, IEEE f32 divide, |x|<0.0004 passthrough
// ---------------------------------------------------------------------------
__device__ __forceinline__ float tanh_xla_fma_f32(float x) {
  const float kClamp = 7.99881172180175781f;
  float xc = fmaxf(x, -kClamp);
  xc = fminf(xc, kClamp);
  float x2 = xc * xc;
  float num = fmaf(x2, -2.76076847742355e-16f, 2.00018790482477e-13f);
  num = fmaf(x2, num, -8.60467152213735e-11f);
  num = fmaf(x2, num, 5.12229709037114e-08f);
  num = fmaf(x2, num, 1.48572235717979e-05f);
  num = fmaf(x2, num, 6.37261928875436e-04f);
  num = fmaf(x2, num, 4.89352455891786e-03f);
  num = xc * num;
  float den = fmaf(x2, 1.19825839466702e-06f, 1.18534705686654e-04f);
  den = fmaf(x2, den, 2.26843463243900e-03f);
  den = fmaf(x2, den, 4.89352518554385e-03f);
  float r = num / den;
  return (fabsf(x) < 0.0004f) ? x : r;
}

// Register plan (gfx950: 256 arch VGPRs + 256 AGPRs, unified 512 budget):
// weights live in AGPRs (plus a few VGPR quads); operand reads are
// SOFTWARE-PIPELINED one quad ahead into two banks (A/B) so the
// v_accvgpr_read / ds_read latency sits in the fma chain's 4-cyc-per-elem
// shadow instead of on it (R10: just-in-time reads -> ~10 cyc/elem).

#define PINV(v) asm("" : "+v"(v));

#define REPA56(M) M(0) M(1) M(2) M(3) M(4) M(5) M(6) M(7) \
  M(8) M(9) M(10) M(11) M(12) M(13) M(14) M(15) \
  M(16) M(17) M(18) M(19) M(20) M(21) M(22) M(23) \
  M(24) M(25) M(26) M(27) M(28) M(29) M(30) M(31) \
  M(32) M(33) M(34) M(35) M(36) M(37) M(38) M(39) \
  M(40) M(41) M(42) M(43) M(44) M(45) M(46) M(47) \
  M(48) M(49) M(50) M(51) M(52) M(53) M(54) M(55)
#define REPV8(M) M(56) M(57) M(58) M(59) M(60) M(61) M(62) M(63)

#define REPA28(M) M(0) M(1) M(2) M(3) M(4) M(5) M(6) M(7) \
  M(8) M(9) M(10) M(11) M(12) M(13) M(14) M(15) \
  M(16) M(17) M(18) M(19) M(20) M(21) M(22) M(23) \
  M(24) M(25) M(26) M(27)
#define REPV4(M) M(28) M(29) M(30) M(31)

#define AG_DECL(n) float ag##n##x, ag##n##y, ag##n##z, ag##n##w;
#define AG_LOAD(n) { f32x4 v = wrow[n]; \
  asm("v_accvgpr_write_b32 %0, %1" : "=a"(ag##n##x) : "v"(v.x)); \
  asm("v_accvgpr_write_b32 %0, %1" : "=a"(ag##n##y) : "v"(v.y)); \
  asm("v_accvgpr_write_b32 %0, %1" : "=a"(ag##n##z) : "v"(v.z)); \
  asm("v_accvgpr_write_b32 %0, %1" : "=a"(ag##n##w) : "v"(v.w)); }
#define VV_DECL(n) f32x4 wv##n;
#define VV_LOAD(n) wv##n = wrow[n]; PINV(wv##n)

// Bank temps: tw<B><0..3> = weight quad, th<B> = operand quad.
#define BANK_DECL(B) float tw##B##0, tw##B##1, tw##B##2, tw##B##3; f32x4 th##B;

// Read quad n (AGPR-resident) into bank B, plus its operand quad from SRC.
// volatile: LICM must not hoist the 224 loop-invariant reads out of the
// step loop (that recreates the >256-arch-VGPR pressure bomb of R8/R9).
#define RQ_A(n, B, SRC) \
  asm volatile("v_accvgpr_read_b32 %0, %1" : "=v"(tw##B##0) : "a"(ag##n##x)); \
  asm volatile("v_accvgpr_read_b32 %0, %1" : "=v"(tw##B##1) : "a"(ag##n##y)); \
  asm volatile("v_accvgpr_read_b32 %0, %1" : "=v"(tw##B##2) : "a"(ag##n##z)); \
  asm volatile("v_accvgpr_read_b32 %0, %1" : "=v"(tw##B##3) : "a"(ag##n##w)); \
  th##B = (SRC)[n];
// Read quad n (VGPR-resident) into bank B.
#define RQ_V(n, B, SRC) \
  tw##B##0 = wv##n.x; tw##B##1 = wv##n.y; tw##B##2 = wv##n.z; tw##B##3 = wv##n.w; \
  th##B = (SRC)[n];
// FROZEN k-ascending fma chain step for one quad from bank B.
#define FQ(B) \
  acc = fmaf(th##B.x, tw##B##0, acc); \
  acc = fmaf(th##B.y, tw##B##1, acc); \
  acc = fmaf(th##B.z, tw##B##2, acc); \
  acc = fmaf(th##B.w, tw##B##3, acc);

#define CH_A(n, BN, BP, SRC) RQ_A(n, BN, SRC) FQ(BP)
#define CH_V(n, BN, BP, SRC) RQ_V(n, BN, SRC) FQ(BP)

// ---------------------------------------------------------------------------
// Kernel A: xw[l][b][h] = sum_i x[b][l][i] * Wx[h][i]
// 28 AGPR quads + 4 pinned VGPR quads; per-iter x-row f32x4 loads pipelined
// one quad ahead (global-load head bubble hidden by 2 waves/SIMD).
// ---------------------------------------------------------------------------
constexpr int LC = 128;   // l-positions per block

__global__ __launch_bounds__(256, 2)
void xw_kernel(const float* __restrict__ x, const float* __restrict__ Wx,
               float* __restrict__ out) {
  const int j  = threadIdx.x;
  const int b  = blockIdx.x & (BATCH - 1);
  const int lt = blockIdx.x >> 6;

  const f32x4* wrow = (const f32x4*)&Wx[(size_t)j * NIN];
  REPA28(AG_DECL)
  REPV4(VV_DECL)
  REPA28(AG_LOAD)
  REPV4(VV_LOAD)

  BANK_DECL(A)
  BANK_DECL(B)

  const float* xr = x + ((size_t)b * LEN + (size_t)lt * LC) * NIN;
  float* op = out + ((size_t)lt * LC * BATCH + b) * NH + j;

  for (int ll = 0; ll < LC; ++ll) {
    const f32x4* xrow = (const f32x4*)(xr + (size_t)ll * NIN);  // uniform
    float acc = 0.0f;
    RQ_A(0, A, xrow)
    CH_A(1,B,A,xrow)  CH_A(2,A,B,xrow)  CH_A(3,B,A,xrow)  CH_A(4,A,B,xrow)
    CH_A(5,B,A,xrow)  CH_A(6,A,B,xrow)  CH_A(7,B,A,xrow)  CH_A(8,A,B,xrow)
    CH_A(9,B,A,xrow)  CH_A(10,A,B,xrow) CH_A(11,B,A,xrow) CH_A(12,A,B,xrow)
    CH_A(13,B,A,xrow) CH_A(14,A,B,xrow) CH_A(15,B,A,xrow) CH_A(16,A,B,xrow)
    CH_A(17,B,A,xrow) CH_A(18,A,B,xrow) CH_A(19,B,A,xrow) CH_A(20,A,B,xrow)
    CH_A(21,B,A,xrow) CH_A(22,A,B,xrow) CH_A(23,B,A,xrow) CH_A(24,A,B,xrow)
    CH_A(25,B,A,xrow) CH_A(26,A,B,xrow) CH_A(27,B,A,xrow)
    CH_V(28,A,B,xrow) CH_V(29,B,A,xrow) CH_V(30,A,B,xrow) CH_V(31,B,A,xrow)
    FQ(B)
    op[(size_t)ll * BATCH * NH] = acc;
  }
}

// ---------------------------------------------------------------------------
// Kernel B: recurrence. One batch/block, 256 threads (1 wave/SIMD,
// launch_bounds(256,1)). W_h row j: 56 AGPR quads + 8 pinned VGPR quads.
// Chain reads (AGPR + LDS h-broadcast) pipelined one quad ahead; frozen
// fma order. lgkmcnt-only barrier (global store stays in flight).
// ---------------------------------------------------------------------------
__global__ __launch_bounds__(256, 1)
void rnn_kernel(const float* __restrict__ Wh, const float* __restrict__ bh,
                const float* __restrict__ h0, float* __restrict__ io) {
  const int b = blockIdx.x;
  const int j = threadIdx.x;

  __shared__ __align__(16) float hbuf[2][NH];

  const f32x4* wrow = (const f32x4*)&Wh[(size_t)j * NH];
  REPA56(AG_DECL)
  REPV8(VV_DECL)
  REPA56(AG_LOAD)
  REPV8(VV_LOAD)

  BANK_DECL(A)
  BANK_DECL(B)

  const float bias = bh[j];
  hbuf[0][j] = h0[b * NH + j];
  __syncthreads();

  float* p = io + (size_t)b * NH + j;
  const size_t stride = (size_t)BATCH * NH;

  float xw = p[0];
  int cur = 0;

  for (int l = 0; l < LEN; ++l) {
    const int ln = (l + 1 < LEN) ? (l + 1) : l;
    const float xw_next = p[(size_t)ln * stride];   // prefetch next xw

    const f32x4* hb = (const f32x4*)&hbuf[cur][0];
    float acc = 0.0f;
    RQ_A(0, A, hb)
    CH_A(1,B,A,hb)  CH_A(2,A,B,hb)  CH_A(3,B,A,hb)  CH_A(4,A,B,hb)
    CH_A(5,B,A,hb)  CH_A(6,A,B,hb)  CH_A(7,B,A,hb)  CH_A(8,A,B,hb)
    CH_A(9,B,A,hb)  CH_A(10,A,B,hb) CH_A(11,B,A,hb) CH_A(12,A,B,hb)
    CH_A(13,B,A,hb) CH_A(14,A,B,hb) CH_A(15,B,A,hb) CH_A(16,A,B,hb)
    CH_A(17,B,A,hb) CH_A(18,A,B,hb) CH_A(19,B,A,hb) CH_A(20,A,B,hb)
    CH_A(21,B,A,hb) CH_A(22,A,B,hb) CH_A(23,B,A,hb) CH_A(24,A,B,hb)
    CH_A(25,B,A,hb) CH_A(26,A,B,hb) CH_A(27,B,A,hb) CH_A(28,A,B,hb)
    CH_A(29,B,A,hb) CH_A(30,A,B,hb) CH_A(31,B,A,hb) CH_A(32,A,B,hb)
    CH_A(33,B,A,hb) CH_A(34,A,B,hb) CH_A(35,B,A,hb) CH_A(36,A,B,hb)
    CH_A(37,B,A,hb) CH_A(38,A,B,hb) CH_A(39,B,A,hb) CH_A(40,A,B,hb)
    CH_A(41,B,A,hb) CH_A(42,A,B,hb) CH_A(43,B,A,hb) CH_A(44,A,B,hb)
    CH_A(45,B,A,hb) CH_A(46,A,B,hb) CH_A(47,B,A,hb) CH_A(48,A,B,hb)
    CH_A(49,B,A,hb) CH_A(50,A,B,hb) CH_A(51,B,A,hb) CH_A(52,A,B,hb)
    CH_A(53,B,A,hb) CH_A(54,A,B,hb) CH_A(55,B,A,hb)
    CH_V(56,A,B,hb) CH_V(57,B,A,hb) CH_V(58,A,B,hb) CH_V(59,B,A,hb)
    CH_V(60,A,B,hb) CH_V(61,B,A,hb) CH_V(62,A,B,hb) CH_V(63,B,A,hb)
    FQ(B)

    float pre;
    {
#pragma clang fp contract(off)
      pre = (xw + acc) + bias;                  // ((xw + hW) + b) order
    }
    const float hn = tanh_xla_fma_f32(pre);

    p[(size_t)l * stride] = hn;                 // fire-and-forget store
    hbuf[cur ^ 1][j] = hn;                      // publish state

    // lgkmcnt-only barrier: LDS visible, global store left in flight.
    asm volatile("s_waitcnt lgkmcnt(0)" ::: "memory");
    __builtin_amdgcn_s_barrier();
    asm volatile("" ::: "memory");

    cur ^= 1;
    xw = xw_next;
  }
}

extern "C" void kernel_launch(void* const* d_in, const int* in_sizes, int n_in,
                              void* d_out, int out_size, void* d_ws, size_t ws_size,
                              hipStream_t stream) {
  // Resolve inputs BY SIZE (all element counts distinct).
  const float* x  = (const float*)d_in[0];  // 16777216
  const float* h0 = (const float*)d_in[1];  // 16384
  const float* Wx = (const float*)d_in[2];  // 32768
  const float* Wh = (const float*)d_in[3];  // 65536
  const float* bh = (const float*)d_in[4];  // 256
  for (int i = 0; i < n_in; ++i) {
    switch (in_sizes[i]) {
      case 16777216: x  = (const float*)d_in[i]; break;
      case 16384:    h0 = (const float*)d_in[i]; break;
      case 32768:    Wx = (const float*)d_in[i]; break;
      case 65536:    Wh = (const float*)d_in[i]; break;
      case 256:      bh = (const float*)d_in[i]; break;
      default: break;
    }
  }
  float* out = (float*)d_out;               // [2048, 64, 256] f32

  xw_kernel<<<dim3((LEN / LC) * BATCH), dim3(256), 0, stream>>>(x, Wx, out);
  rnn_kernel<<<dim3(BATCH), dim3(256), 0, stream>>>(Wh, bh, h0, out);
}

// Round 12
// 2617.427 us; speedup vs baseline: 2.0792x; 1.3917x over previous
//
#include <hip/hip_runtime.h>

#define BATCH 64
#define LEN   2048
#define NIN   128
#define NH    256

typedef float f32x4 __attribute__((ext_vector_type(4)));
typedef float f32x2 __attribute__((ext_vector_type(2)));

// ---------------------------------------------------------------------------
// FROZEN ARITHMETIC (R7: absmax == 0.0). Do not touch:
//  - dots: single-accumulator, k-ascending fmaf chains from 0
//  - pre = (xw + acc) + bias, left-assoc, no contraction
//  - tanh = EmitFastTanh(with_fma=true): clamp ±7.99881172180175781,
//    fmaf Horner, IEEE f32 divide, |x|<0.0004 passthrough
// ---------------------------------------------------------------------------
__device__ __forceinline__ float tanh_xla_fma_f32(float x) {
  const float kClamp = 7.99881172180175781f;
  float xc = fmaxf(x, -kClamp);
  xc = fminf(xc, kClamp);
  float x2 = xc * xc;
  float num = fmaf(x2, -2.76076847742355e-16f, 2.00018790482477e-13f);
  num = fmaf(x2, num, -8.60467152213735e-11f);
  num = fmaf(x2, num, 5.12229709037114e-08f);
  num = fmaf(x2, num, 1.48572235717979e-05f);
  num = fmaf(x2, num, 6.37261928875436e-04f);
  num = fmaf(x2, num, 4.89352455891786e-03f);
  num = xc * num;
  float den = fmaf(x2, 1.19825839466702e-06f, 1.18534705686654e-04f);
  den = fmaf(x2, den, 2.26843463243900e-03f);
  den = fmaf(x2, den, 4.89352518554385e-03f);
  float r = num / den;
  return (fabsf(x) < 0.0004f) ? x : r;
}

#define PINV(v) asm("" : "+v"(v));

// Broadcast via the VALU lane crossbar, not the LDS pipe (R10/R11 lesson:
// all-lane-same-address ds_read_b128 replicates 1024B/instr through the
// shared LDS pipe -> ~3000 cyc/step). readlane is bit-exact data movement.
#define RLANE(val, q) \
  __uint_as_float(__builtin_amdgcn_readlane(__float_as_uint(val), (q)))

#define REPQ48(M) M(0) M(1) M(2) M(3) M(4) M(5) M(6) M(7) \
  M(8) M(9) M(10) M(11) M(12) M(13) M(14) M(15) \
  M(16) M(17) M(18) M(19) M(20) M(21) M(22) M(23) \
  M(24) M(25) M(26) M(27) M(28) M(29) M(30) M(31) \
  M(32) M(33) M(34) M(35) M(36) M(37) M(38) M(39) \
  M(40) M(41) M(42) M(43) M(44) M(45) M(46) M(47)
#define REPQ16(M) M(48) M(49) M(50) M(51) M(52) M(53) M(54) M(55) \
  M(56) M(57) M(58) M(59) M(60) M(61) M(62) M(63)
#define REPX32(M) M(0) M(1) M(2) M(3) M(4) M(5) M(6) M(7) \
  M(8) M(9) M(10) M(11) M(12) M(13) M(14) M(15) \
  M(16) M(17) M(18) M(19) M(20) M(21) M(22) M(23) \
  M(24) M(25) M(26) M(27) M(28) M(29) M(30) M(31)

// VGPR-resident weight quads (pinned: no remat)
#define WQ_DECL(n) f32x4 wq##n;
#define WQ_LOAD(n) wq##n = wrow[n]; PINV(wq##n)
// AGPR-resident weight quads (arch-VGPR cap relief; reads volatile so LICM
// can't hoist them out of the step loop)
#define AQ_DECL(n) float aq##n##x, aq##n##y, aq##n##z, aq##n##w;
#define AQ_LOAD(n) { f32x4 v = wrow[n]; \
  asm("v_accvgpr_write_b32 %0, %1" : "=a"(aq##n##x) : "v"(v.x)); \
  asm("v_accvgpr_write_b32 %0, %1" : "=a"(aq##n##y) : "v"(v.y)); \
  asm("v_accvgpr_write_b32 %0, %1" : "=a"(aq##n##z) : "v"(v.z)); \
  asm("v_accvgpr_write_b32 %0, %1" : "=a"(aq##n##w) : "v"(v.w)); }

// FROZEN k-ascending chain, one quad (h[4n..4n+3] = lane n of hq.x/y/z/w)
#define STEPV(n) \
  acc = fmaf(RLANE(hq.x, n), wq##n.x, acc); \
  acc = fmaf(RLANE(hq.y, n), wq##n.y, acc); \
  acc = fmaf(RLANE(hq.z, n), wq##n.z, acc); \
  acc = fmaf(RLANE(hq.w, n), wq##n.w, acc);
#define STEPA(n) { float t0, t1, t2, t3; \
  asm volatile("v_accvgpr_read_b32 %0, %1" : "=v"(t0) : "a"(aq##n##x)); \
  asm volatile("v_accvgpr_read_b32 %0, %1" : "=v"(t1) : "a"(aq##n##y)); \
  asm volatile("v_accvgpr_read_b32 %0, %1" : "=v"(t2) : "a"(aq##n##z)); \
  asm volatile("v_accvgpr_read_b32 %0, %1" : "=v"(t3) : "a"(aq##n##w)); \
  acc = fmaf(RLANE(hq.x, n), t0, acc); \
  acc = fmaf(RLANE(hq.y, n), t1, acc); \
  acc = fmaf(RLANE(hq.z, n), t2, acc); \
  acc = fmaf(RLANE(hq.w, n), t3, acc); }

// ---------------------------------------------------------------------------
// Kernel A: xw[l][b][h] = sum_i x[b][l][i] * Wx[h][i]
// One coalesced global_load_dwordx2/lane per row (lane i: x[2i],x[2i+1]);
// elements broadcast via readlane. 32 weight quads in VGPRs (~150 regs,
// 3 waves/SIMD). Strict i-ascending fmaf chain (frozen).
// x[4n..4n+3] = lanes 2n,2n,2n+1,2n+1, comps x,y,x,y.
// ---------------------------------------------------------------------------
#define XSTEP(n) \
  acc = fmaf(RLANE(xv.x, 2*(n)    ), wq##n.x, acc); \
  acc = fmaf(RLANE(xv.y, 2*(n)    ), wq##n.y, acc); \
  acc = fmaf(RLANE(xv.x, 2*(n) + 1), wq##n.z, acc); \
  acc = fmaf(RLANE(xv.y, 2*(n) + 1), wq##n.w, acc);

constexpr int LC = 128;   // l-positions per block

__global__ __launch_bounds__(256, 2)
void xw_kernel(const float* __restrict__ x, const float* __restrict__ Wx,
               float* __restrict__ out) {
  const int j    = threadIdx.x;
  const int lane = j & 63;
  const int b    = blockIdx.x & (BATCH - 1);
  const int lt   = blockIdx.x >> 6;

  const f32x4* wrow = (const f32x4*)&Wx[(size_t)j * NIN];
  REPX32(WQ_DECL)
  REPX32(WQ_LOAD)

  const float* xr = x + ((size_t)b * LEN + (size_t)lt * LC) * NIN;
  float* op = out + ((size_t)lt * LC * BATCH + b) * NH + j;

  f32x2 xv = *(const f32x2*)(xr + 2 * lane);       // row 0, coalesced
  for (int ll = 0; ll < LC; ++ll) {
    const int ln = (ll + 1 < LC) ? (ll + 1) : ll;
    f32x2 xnext = *(const f32x2*)(xr + (size_t)ln * NIN + 2 * lane);
    float acc = 0.0f;
    REPX32(XSTEP)
    op[(size_t)ll * BATCH * NH] = acc;
    xv = xnext;
  }
}

// ---------------------------------------------------------------------------
// Kernel B: recurrence. One batch/block, 256 threads (1 wave/SIMD,
// launch_bounds(256,1)). Weights: 48 VGPR quads + 16 AGPR quads (~220 arch
// VGPR + 64 AGPR — feasible, unlike R8/R9's 296). Per step: ONE coalesced
// ds_read_b128/wave (h -> 4 VGPRs), then 256 readlane+fma in the chain's
// latency shadow. lgkmcnt-only barrier (global store stays in flight).
// ---------------------------------------------------------------------------
__global__ __launch_bounds__(256, 1)
void rnn_kernel(const float* __restrict__ Wh, const float* __restrict__ bh,
                const float* __restrict__ h0, float* __restrict__ io) {
  const int b    = blockIdx.x;
  const int j    = threadIdx.x;
  const int lane = j & 63;

  __shared__ __align__(16) float hbuf[2][NH];

  const f32x4* wrow = (const f32x4*)&Wh[(size_t)j * NH];
  REPQ48(WQ_DECL)
  REPQ16(AQ_DECL)
  REPQ48(WQ_LOAD)
  REPQ16(AQ_LOAD)

  const float bias = bh[j];
  hbuf[0][j] = h0[b * NH + j];
  __syncthreads();

  float* p = io + (size_t)b * NH + j;
  const size_t stride = (size_t)BATCH * NH;

  float xw = p[0];
  int cur = 0;

  for (int l = 0; l < LEN; ++l) {
    const int ln = (l + 1 < LEN) ? (l + 1) : l;
    const float xw_next = p[(size_t)ln * stride];   // prefetch next xw

    const f32x4 hq = *(const f32x4*)&hbuf[cur][4 * lane];  // 1 coalesced read
    float acc = 0.0f;
    REPQ48(STEPV)
    REPQ16(STEPA)

    float pre;
    {
#pragma clang fp contract(off)
      pre = (xw + acc) + bias;                  // ((xw + hW) + b) order
    }
    const float hn = tanh_xla_fma_f32(pre);

    p[(size_t)l * stride] = hn;                 // fire-and-forget store
    hbuf[cur ^ 1][j] = hn;                      // publish state

    // lgkmcnt-only barrier: LDS visible, global store left in flight.
    asm volatile("s_waitcnt lgkmcnt(0)" ::: "memory");
    __builtin_amdgcn_s_barrier();
    asm volatile("" ::: "memory");

    cur ^= 1;
    xw = xw_next;
  }
}

extern "C" void kernel_launch(void* const* d_in, const int* in_sizes, int n_in,
                              void* d_out, int out_size, void* d_ws, size_t ws_size,
                              hipStream_t stream) {
  // Resolve inputs BY SIZE (all element counts distinct).
  const float* x  = (const float*)d_in[0];  // 16777216
  const float* h0 = (const float*)d_in[1];  // 16384
  const float* Wx = (const float*)d_in[2];  // 32768
  const float* Wh = (const float*)d_in[3];  // 65536
  const float* bh = (const float*)d_in[4];  // 256
  for (int i = 0; i < n_in; ++i) {
    switch (in_sizes[i]) {
      case 16777216: x  = (const float*)d_in[i]; break;
      case 16384:    h0 = (const float*)d_in[i]; break;
      case 32768:    Wx = (const float*)d_in[i]; break;
      case 65536:    Wh = (const float*)d_in[i]; break;
      case 256:      bh = (const float*)d_in[i]; break;
      default: break;
    }
  }
  float* out = (float*)d_out;               // [2048, 64, 256] f32

  xw_kernel<<<dim3((LEN / LC) * BATCH), dim3(256), 0, stream>>>(x, Wx, out);
  rnn_kernel<<<dim3(BATCH), dim3(256), 0, stream>>>(Wh, bh, h0, out);
}